// Round 4
// baseline (219.826 us; speedup 1.0000x reference)
//
#include <hip/hip_runtime.h>
#include <math.h>

#define KBT 2.494338785445972f
#define CH 8

typedef float f4 __attribute__((ext_vector_type(4)));

struct F3 { float x, y, z; };
__device__ inline F3 f3sub(F3 a, F3 b) { return {a.x - b.x, a.y - b.y, a.z - b.z}; }
__device__ inline F3 f3cross(F3 a, F3 b) {
    return {a.y * b.z - a.z * b.y, a.z * b.x - a.x * b.z, a.x * b.y - a.y * b.x};
}
__device__ inline float f3dot(F3 a, F3 b) { return a.x * b.x + a.y * b.y + a.z * b.z; }
__device__ inline F3 ldp(const float* __restrict__ p, int i) {
    return {p[3 * i], p[3 * i + 1], p[3 * i + 2]};
}

// Kernel 1: features x = [cos(angles) (A), cos(dih) (D), sin(dih) (D)]
__global__ __launch_bounds__(256) void feat_kernel(
    const float* __restrict__ pos, const int* __restrict__ aidx,
    const int* __restrict__ didx, float* __restrict__ x, int A, int D) {
    int i = blockIdx.x * blockDim.x + threadIdx.x;
    if (i < A) {
        int i0 = aidx[3 * i], i1 = aidx[3 * i + 1], i2 = aidx[3 * i + 2];
        F3 p0 = ldp(pos, i0), p1 = ldp(pos, i1), p2 = ldp(pos, i2);
        F3 v0 = f3sub(p0, p1), v1 = f3sub(p2, p1);
        float d = f3dot(v0, v1);
        F3 c = f3cross(v0, v1);
        float r = sqrtf(d * d + f3dot(c, c));   // = |v0||v1|
        x[i] = d / r;                            // cos(atan2(|c|, d))
    } else if (i < A + D) {
        int j = i - A;
        int i0 = didx[4 * j], i1 = didx[4 * j + 1], i2 = didx[4 * j + 2], i3 = didx[4 * j + 3];
        F3 p0 = ldp(pos, i0), p1 = ldp(pos, i1), p2 = ldp(pos, i2), p3 = ldp(pos, i3);
        F3 b1v = f3sub(p1, p0), b2v = f3sub(p2, p1), b3v = f3sub(p3, p2);
        F3 n1 = f3cross(b1v, b2v), n2 = f3cross(b2v, b3v);
        float xc = f3dot(n1, n2);                          // cos-like term
        float b2n = sqrtf(f3dot(b2v, b2v));
        F3 cr = f3cross(n1, n2);
        float yc = f3dot(cr, b2v) / b2n;                   // sin-like term
        float r = sqrtf(xc * xc + yc * yc);
        x[A + j] = xc / r;        // cos(dihedral)
        x[A + D + j] = yc / r;    // sin(dihedral)
    }
}

// Kernel 2: y1 partials. grid = (H rows, CH chunks). No atomics.
__global__ __launch_bounds__(256) void w1_kernel(
    const float* __restrict__ W1, const float* __restrict__ x,
    float* __restrict__ partial, int F) {
    int r = blockIdx.x;
    int c = blockIdx.y;
    int F4 = F >> 2;
    const f4* __restrict__ row = (const f4*)(W1 + (size_t)r * F);
    const f4* __restrict__ xv = (const f4*)x;
    int per = (F4 + CH - 1) / CH;
    int s = c * per;
    int e = min(s + per, F4);
    float acc = 0.0f;
    for (int k = s + (int)threadIdx.x; k < e; k += 256) {
        f4 w = __builtin_nontemporal_load(&row[k]);
        f4 v = xv[k];
        acc = fmaf(w.x, v.x, fmaf(w.y, v.y, fmaf(w.z, v.z, fmaf(w.w, v.w, acc))));
    }
    if (c == CH - 1) {  // scalar tail if F % 4 != 0 (not hit for F=299992)
        for (int k = (F4 << 2) + (int)threadIdx.x; k < F; k += 256)
            acc = fmaf(W1[(size_t)r * F + k], x[k], acc);
    }
    // wave reduce (64 lanes), then cross-wave via LDS
    #pragma unroll
    for (int off = 32; off; off >>= 1) acc += __shfl_down(acc, off);
    __shared__ float lds[4];
    int wave = threadIdx.x >> 6, lane = threadIdx.x & 63;
    if (lane == 0) lds[wave] = acc;
    __syncthreads();
    if (threadIdx.x == 0) partial[r * CH + c] = lds[0] + lds[1] + lds[2] + lds[3];
}

// Kernel 3: reduce partials + bias + tanh, layers 2/3, W4 dot, scale.
__global__ __launch_bounds__(1024) void tail_kernel(
    const float* __restrict__ partial, const float* __restrict__ b1,
    const float* __restrict__ W2, const float* __restrict__ b2,
    const float* __restrict__ W3, const float* __restrict__ b3,
    const float* __restrict__ W4, float* __restrict__ out) {
    __shared__ float xa[256];
    __shared__ float xb[256];
    __shared__ float red[1024];
    __shared__ float lds4[16];
    int t = threadIdx.x;
    int row = t >> 2, part = t & 3;

    if (t < 256) {
        float s = 0.0f;
        #pragma unroll
        for (int c = 0; c < CH; ++c) s += partial[t * CH + c];
        xa[t] = tanhf(s + b1[t]);
    }
    __syncthreads();

    {
        const f4* __restrict__ W2v = (const f4*)W2 + (row << 6) + (part << 4);
        float acc = 0.0f;
        #pragma unroll
        for (int k = 0; k < 16; ++k) {
            f4 w = W2v[k];
            int base = (part << 6) + (k << 2);
            acc += w.x * xa[base] + w.y * xa[base + 1] + w.z * xa[base + 2] + w.w * xa[base + 3];
        }
        red[t] = acc;
    }
    __syncthreads();
    if (t < 256)
        xb[t] = tanhf(red[4 * t] + red[4 * t + 1] + red[4 * t + 2] + red[4 * t + 3] + b2[t]);
    __syncthreads();

    {
        const f4* __restrict__ W3v = (const f4*)W3 + (row << 6) + (part << 4);
        float acc = 0.0f;
        #pragma unroll
        for (int k = 0; k < 16; ++k) {
            f4 w = W3v[k];
            int base = (part << 6) + (k << 2);
            acc += w.x * xb[base] + w.y * xb[base + 1] + w.z * xb[base + 2] + w.w * xb[base + 3];
        }
        red[t] = acc;
    }
    __syncthreads();

    float v = 0.0f;
    if (t < 256) {
        float x3 = tanhf(red[4 * t] + red[4 * t + 1] + red[4 * t + 2] + red[4 * t + 3] + b3[t]);
        v = W4[t] * x3;
    }
    #pragma unroll
    for (int off = 32; off; off >>= 1) v += __shfl_down(v, off);
    if ((t & 63) == 0) lds4[t >> 6] = v;
    __syncthreads();
    if (t == 0) out[0] = KBT * (lds4[0] + lds4[1] + lds4[2] + lds4[3]);
}

extern "C" void kernel_launch(void* const* d_in, const int* in_sizes, int n_in,
                              void* d_out, int out_size, void* d_ws, size_t ws_size,
                              hipStream_t stream) {
    const float* pos  = (const float*)d_in[0];
    const int*   aidx = (const int*)d_in[1];
    const int*   didx = (const int*)d_in[2];
    const float* W1   = (const float*)d_in[3];
    const float* b1   = (const float*)d_in[4];
    const float* W2   = (const float*)d_in[5];
    const float* b2   = (const float*)d_in[6];
    const float* W3   = (const float*)d_in[7];
    const float* b3   = (const float*)d_in[8];
    const float* W4   = (const float*)d_in[9];

    int A = in_sizes[1] / 3;
    int D = in_sizes[2] / 4;
    int F = A + 2 * D;

    float* ws = (float*)d_ws;
    float* x = ws;                              // F floats
    float* partial = ws + ((F + 3) & ~3);       // 256*CH floats

    int total = A + D;
    feat_kernel<<<(total + 255) / 256, 256, 0, stream>>>(pos, aidx, didx, x, A, D);

    // MEASUREMENT ROUND: w1 launched 3x (identical outputs, deterministic).
    // dur_R4 - dur_R3 = 2 * w1_time. Remove duplicates next round.
    dim3 g(256, CH);
    w1_kernel<<<g, 256, 0, stream>>>(W1, x, partial, F);
    w1_kernel<<<g, 256, 0, stream>>>(W1, x, partial, F);
    w1_kernel<<<g, 256, 0, stream>>>(W1, x, partial, F);

    tail_kernel<<<1, 1024, 0, stream>>>(partial, b1, W2, b2, W3, b3, W4, (float*)d_out);
}

// Round 5
// 75.998 us; speedup vs baseline: 2.8925x; 2.8925x over previous
//
#include <hip/hip_runtime.h>
#include <math.h>

#define KBT 2.494338785445972f
#define CH 8

typedef float f4 __attribute__((ext_vector_type(4)));

struct F3 { float x, y, z; };
__device__ inline F3 f3sub(F3 a, F3 b) { return {a.x - b.x, a.y - b.y, a.z - b.z}; }
__device__ inline F3 f3cross(F3 a, F3 b) {
    return {a.y * b.z - a.z * b.y, a.z * b.x - a.x * b.z, a.x * b.y - a.y * b.x};
}
__device__ inline float f3dot(F3 a, F3 b) { return a.x * b.x + a.y * b.y + a.z * b.z; }
__device__ inline F3 ldp(const float* __restrict__ p, int i) {
    return {p[3 * i], p[3 * i + 1], p[3 * i + 2]};
}
__device__ inline float dot4(f4 w, f4 v, float acc) {
    return fmaf(w.x, v.x, fmaf(w.y, v.y, fmaf(w.z, v.z, fmaf(w.w, v.w, acc))));
}

// Kernel 1: features x = [cos(angles) (A), cos(dih) (D), sin(dih) (D)]
__global__ __launch_bounds__(256) void feat_kernel(
    const float* __restrict__ pos, const int* __restrict__ aidx,
    const int* __restrict__ didx, float* __restrict__ x, int A, int D) {
    int i = blockIdx.x * blockDim.x + threadIdx.x;
    if (i < A) {
        int i0 = aidx[3 * i], i1 = aidx[3 * i + 1], i2 = aidx[3 * i + 2];
        F3 p0 = ldp(pos, i0), p1 = ldp(pos, i1), p2 = ldp(pos, i2);
        F3 v0 = f3sub(p0, p1), v1 = f3sub(p2, p1);
        float d = f3dot(v0, v1);
        F3 c = f3cross(v0, v1);
        float r = sqrtf(d * d + f3dot(c, c));   // = |v0||v1|
        x[i] = d / r;                            // cos(atan2(|c|, d))
    } else if (i < A + D) {
        int j = i - A;
        int i0 = didx[4 * j], i1 = didx[4 * j + 1], i2 = didx[4 * j + 2], i3 = didx[4 * j + 3];
        F3 p0 = ldp(pos, i0), p1 = ldp(pos, i1), p2 = ldp(pos, i2), p3 = ldp(pos, i3);
        F3 b1v = f3sub(p1, p0), b2v = f3sub(p2, p1), b3v = f3sub(p3, p2);
        F3 n1 = f3cross(b1v, b2v), n2 = f3cross(b2v, b3v);
        float xc = f3dot(n1, n2);                          // cos-like term
        float b2n = sqrtf(f3dot(b2v, b2v));
        F3 cr = f3cross(n1, n2);
        float yc = f3dot(cr, b2v) / b2n;                   // sin-like term
        float r = sqrtf(xc * xc + yc * yc);
        x[A + j] = xc / r;        // cos(dihedral)
        x[A + D + j] = yc / r;    // sin(dihedral)
    }
}

// Kernel 2: y1 partials. grid = (H rows, CH chunks). Unroll x4 with 4
// independent accumulators -> 4+ outstanding HBM loads per thread.
__global__ __launch_bounds__(256) void w1_kernel(
    const float* __restrict__ W1, const float* __restrict__ x,
    float* __restrict__ partial, int F) {
    int r = blockIdx.x;
    int c = blockIdx.y;
    int F4 = F >> 2;
    const f4* __restrict__ row = (const f4*)(W1 + (size_t)r * F);
    const f4* __restrict__ xv = (const f4*)x;
    int per = (F4 + CH - 1) / CH;
    int s = c * per;
    int e = min(s + per, F4);
    float a0 = 0.0f, a1 = 0.0f, a2 = 0.0f, a3 = 0.0f;
    int k = s + (int)threadIdx.x;
    for (; k + 768 < e; k += 1024) {
        f4 w0 = __builtin_nontemporal_load(&row[k]);
        f4 w1 = __builtin_nontemporal_load(&row[k + 256]);
        f4 w2 = __builtin_nontemporal_load(&row[k + 512]);
        f4 w3 = __builtin_nontemporal_load(&row[k + 768]);
        f4 v0 = xv[k];
        f4 v1 = xv[k + 256];
        f4 v2 = xv[k + 512];
        f4 v3 = xv[k + 768];
        a0 = dot4(w0, v0, a0);
        a1 = dot4(w1, v1, a1);
        a2 = dot4(w2, v2, a2);
        a3 = dot4(w3, v3, a3);
    }
    for (; k < e; k += 256) {
        f4 w = __builtin_nontemporal_load(&row[k]);
        a0 = dot4(w, xv[k], a0);
    }
    if (c == CH - 1) {  // scalar tail if F % 4 != 0 (not hit for F=299992)
        for (int q = (F4 << 2) + (int)threadIdx.x; q < F; q += 256)
            a0 = fmaf(W1[(size_t)r * F + q], x[q], a0);
    }
    float acc = (a0 + a1) + (a2 + a3);
    #pragma unroll
    for (int off = 32; off; off >>= 1) acc += __shfl_down(acc, off);
    __shared__ float lds[4];
    int wave = threadIdx.x >> 6, lane = threadIdx.x & 63;
    if (lane == 0) lds[wave] = acc;
    __syncthreads();
    if (threadIdx.x == 0) partial[r * CH + c] = lds[0] + lds[1] + lds[2] + lds[3];
}

// Kernel 3: layer 2, one block per output row (weights fetched in parallel
// across 256 CUs). Each block redundantly finishes layer 1 from L2-hot
// partials (cheap) so no extra launch is needed.
__global__ __launch_bounds__(256) void l2_kernel(
    const float* __restrict__ partial, const float* __restrict__ b1,
    const float* __restrict__ W2, const float* __restrict__ b2,
    float* __restrict__ xb) {
    __shared__ float xa[256];
    __shared__ float lds[4];
    int t = threadIdx.x, r = blockIdx.x;
    float s = 0.0f;
    #pragma unroll
    for (int c = 0; c < CH; ++c) s += partial[t * CH + c];
    xa[t] = tanhf(s + b1[t]);
    __syncthreads();
    float v = W2[(r << 8) + t] * xa[t];
    #pragma unroll
    for (int off = 32; off; off >>= 1) v += __shfl_down(v, off);
    if ((t & 63) == 0) lds[t >> 6] = v;
    __syncthreads();
    if (t == 0) xb[r] = tanhf(lds[0] + lds[1] + lds[2] + lds[3] + b2[r]);
}

// Kernel 4: layer 3 + W4 elementwise, one block per row.
__global__ __launch_bounds__(256) void l3_kernel(
    const float* __restrict__ xb, const float* __restrict__ W3,
    const float* __restrict__ b3, const float* __restrict__ W4,
    float* __restrict__ w4term) {
    __shared__ float lds[4];
    int t = threadIdx.x, r = blockIdx.x;
    float v = W3[(r << 8) + t] * xb[t];
    #pragma unroll
    for (int off = 32; off; off >>= 1) v += __shfl_down(v, off);
    if ((t & 63) == 0) lds[t >> 6] = v;
    __syncthreads();
    if (t == 0) w4term[r] = W4[r] * tanhf(lds[0] + lds[1] + lds[2] + lds[3] + b3[r]);
}

// Kernel 5: final 256 -> scalar
__global__ __launch_bounds__(256) void out_kernel(
    const float* __restrict__ w4term, float* __restrict__ out) {
    __shared__ float lds[4];
    int t = threadIdx.x;
    float v = w4term[t];
    #pragma unroll
    for (int off = 32; off; off >>= 1) v += __shfl_down(v, off);
    if ((t & 63) == 0) lds[t >> 6] = v;
    __syncthreads();
    if (t == 0) out[0] = KBT * (lds[0] + lds[1] + lds[2] + lds[3]);
}

extern "C" void kernel_launch(void* const* d_in, const int* in_sizes, int n_in,
                              void* d_out, int out_size, void* d_ws, size_t ws_size,
                              hipStream_t stream) {
    const float* pos  = (const float*)d_in[0];
    const int*   aidx = (const int*)d_in[1];
    const int*   didx = (const int*)d_in[2];
    const float* W1   = (const float*)d_in[3];
    const float* b1   = (const float*)d_in[4];
    const float* W2   = (const float*)d_in[5];
    const float* b2   = (const float*)d_in[6];
    const float* W3   = (const float*)d_in[7];
    const float* b3   = (const float*)d_in[8];
    const float* W4   = (const float*)d_in[9];

    int A = in_sizes[1] / 3;
    int D = in_sizes[2] / 4;
    int F = A + 2 * D;

    float* ws = (float*)d_ws;
    float* x = ws;                              // F floats
    float* partial = ws + ((F + 3) & ~3);       // 256*CH floats
    float* xb = partial + 256 * CH;             // 256 floats
    float* w4term = xb + 256;                   // 256 floats

    int total = A + D;
    feat_kernel<<<(total + 255) / 256, 256, 0, stream>>>(pos, aidx, didx, x, A, D);

    dim3 g(256, CH);
    w1_kernel<<<g, 256, 0, stream>>>(W1, x, partial, F);

    l2_kernel<<<256, 256, 0, stream>>>(partial, b1, W2, b2, xb);
    l3_kernel<<<256, 256, 0, stream>>>(xb, W3, b3, W4, w4term);
    out_kernel<<<1, 256, 0, stream>>>(w4term, (float*)d_out);
}

// Round 6
// 72.311 us; speedup vs baseline: 3.0400x; 1.0510x over previous
//
#include <hip/hip_runtime.h>
#include <math.h>

#define KBT 2.494338785445972f
#define CHUNK 1024  // f4 elements of one W1 row per block

typedef float f4 __attribute__((ext_vector_type(4)));

struct F3 { float x, y, z; };
__device__ inline F3 f3sub(F3 a, F3 b) { return {a.x - b.x, a.y - b.y, a.z - b.z}; }
__device__ inline F3 f3cross(F3 a, F3 b) {
    return {a.y * b.z - a.z * b.y, a.z * b.x - a.x * b.z, a.x * b.y - a.y * b.x};
}
__device__ inline float f3dot(F3 a, F3 b) { return a.x * b.x + a.y * b.y + a.z * b.z; }
__device__ inline F3 ldp(const float* __restrict__ p, int i) {
    return {p[3 * i], p[3 * i + 1], p[3 * i + 2]};
}
__device__ inline float dot4(f4 w, f4 v, float acc) {
    return fmaf(w.x, v.x, fmaf(w.y, v.y, fmaf(w.z, v.z, fmaf(w.w, v.w, acc))));
}

// Kernel 1: features x = [cos(angles) (A), cos(dih) (D), sin(dih) (D)]
__global__ __launch_bounds__(256) void feat_kernel(
    const float* __restrict__ pos, const int* __restrict__ aidx,
    const int* __restrict__ didx, float* __restrict__ x, int A, int D) {
    int i = blockIdx.x * blockDim.x + threadIdx.x;
    if (i < A) {
        int i0 = aidx[3 * i], i1 = aidx[3 * i + 1], i2 = aidx[3 * i + 2];
        F3 p0 = ldp(pos, i0), p1 = ldp(pos, i1), p2 = ldp(pos, i2);
        F3 v0 = f3sub(p0, p1), v1 = f3sub(p2, p1);
        float d = f3dot(v0, v1);
        F3 c = f3cross(v0, v1);
        float r = sqrtf(d * d + f3dot(c, c));   // = |v0||v1|
        x[i] = d / r;                            // cos(atan2(|c|, d))
    } else if (i < A + D) {
        int j = i - A;
        int i0 = didx[4 * j], i1 = didx[4 * j + 1], i2 = didx[4 * j + 2], i3 = didx[4 * j + 3];
        F3 p0 = ldp(pos, i0), p1 = ldp(pos, i1), p2 = ldp(pos, i2), p3 = ldp(pos, i3);
        F3 b1v = f3sub(p1, p0), b2v = f3sub(p2, p1), b3v = f3sub(p3, p2);
        F3 n1 = f3cross(b1v, b2v), n2 = f3cross(b2v, b3v);
        float xc = f3dot(n1, n2);                          // cos-like term
        float b2n = sqrtf(f3dot(b2v, b2v));
        F3 cr = f3cross(n1, n2);
        float yc = f3dot(cr, b2v) / b2n;                   // sin-like term
        float r = sqrtf(xc * xc + yc * yc);
        x[A + j] = xc / r;        // cos(dihedral)
        x[A + D + j] = yc / r;    // sin(dihedral)
    }
}

// Kernel 2: y1 partials, linear-sweep layout.
// grid = (NCH chunks, 256 rows); blockIdx.x fastest -> global dispatch order
// walks W1 linearly like a fill/copy kernel (one interleaved DRAM stream).
// Each block: 16KB contiguous W1 (nt) + 16KB L2-hot x slice, 4 f4/thread.
__global__ __launch_bounds__(256) void w1_kernel(
    const float* __restrict__ W1, const float* __restrict__ x,
    float* __restrict__ partial, int F4, int NCH) {
    int c = blockIdx.x, r = blockIdx.y;
    const f4* __restrict__ row = (const f4*)W1 + (size_t)r * F4;
    const f4* __restrict__ xv = (const f4*)x;
    int i0 = c * CHUNK + (int)threadIdx.x;
    int i1 = i0 + 256, i2 = i0 + 512, i3 = i0 + 768;
    float a0 = 0.0f, a1 = 0.0f, a2 = 0.0f, a3 = 0.0f;
    if (i0 < F4) a0 = dot4(__builtin_nontemporal_load(&row[i0]), xv[i0], a0);
    if (i1 < F4) a1 = dot4(__builtin_nontemporal_load(&row[i1]), xv[i1], a1);
    if (i2 < F4) a2 = dot4(__builtin_nontemporal_load(&row[i2]), xv[i2], a2);
    if (i3 < F4) a3 = dot4(__builtin_nontemporal_load(&row[i3]), xv[i3], a3);
    float acc = (a0 + a1) + (a2 + a3);
    #pragma unroll
    for (int off = 32; off; off >>= 1) acc += __shfl_down(acc, off);
    __shared__ float lds[4];
    int wave = threadIdx.x >> 6, lane = threadIdx.x & 63;
    if (lane == 0) lds[wave] = acc;
    __syncthreads();
    if (threadIdx.x == 0) partial[r * NCH + c] = lds[0] + lds[1] + lds[2] + lds[3];
}

// Kernel 3: layer 2, one block per output row. Each block redundantly
// finishes layer 1 from L2-hot partials.
__global__ __launch_bounds__(256) void l2_kernel(
    const float* __restrict__ partial, const float* __restrict__ b1,
    const float* __restrict__ W2, const float* __restrict__ b2,
    float* __restrict__ xb, int NCH) {
    __shared__ float xa[256];
    __shared__ float lds[4];
    int t = threadIdx.x, r = blockIdx.x;
    float s = 0.0f;
    #pragma unroll 8
    for (int c = 0; c < NCH; ++c) s += partial[t * NCH + c];
    xa[t] = tanhf(s + b1[t]);
    __syncthreads();
    float v = W2[(r << 8) + t] * xa[t];
    #pragma unroll
    for (int off = 32; off; off >>= 1) v += __shfl_down(v, off);
    if ((t & 63) == 0) lds[t >> 6] = v;
    __syncthreads();
    if (t == 0) xb[r] = tanhf(lds[0] + lds[1] + lds[2] + lds[3] + b2[r]);
}

// Kernel 4: layer 3 + W4 elementwise, one block per row.
__global__ __launch_bounds__(256) void l3_kernel(
    const float* __restrict__ xb, const float* __restrict__ W3,
    const float* __restrict__ b3, const float* __restrict__ W4,
    float* __restrict__ w4term) {
    __shared__ float lds[4];
    int t = threadIdx.x, r = blockIdx.x;
    float v = W3[(r << 8) + t] * xb[t];
    #pragma unroll
    for (int off = 32; off; off >>= 1) v += __shfl_down(v, off);
    if ((t & 63) == 0) lds[t >> 6] = v;
    __syncthreads();
    if (t == 0) w4term[r] = W4[r] * tanhf(lds[0] + lds[1] + lds[2] + lds[3] + b3[r]);
}

// Kernel 5: final 256 -> scalar
__global__ __launch_bounds__(256) void out_kernel(
    const float* __restrict__ w4term, float* __restrict__ out) {
    __shared__ float lds[4];
    int t = threadIdx.x;
    float v = w4term[t];
    #pragma unroll
    for (int off = 32; off; off >>= 1) v += __shfl_down(v, off);
    if ((t & 63) == 0) lds[t >> 6] = v;
    __syncthreads();
    if (t == 0) out[0] = KBT * (lds[0] + lds[1] + lds[2] + lds[3]);
}

extern "C" void kernel_launch(void* const* d_in, const int* in_sizes, int n_in,
                              void* d_out, int out_size, void* d_ws, size_t ws_size,
                              hipStream_t stream) {
    const float* pos  = (const float*)d_in[0];
    const int*   aidx = (const int*)d_in[1];
    const int*   didx = (const int*)d_in[2];
    const float* W1   = (const float*)d_in[3];
    const float* b1   = (const float*)d_in[4];
    const float* W2   = (const float*)d_in[5];
    const float* b2   = (const float*)d_in[6];
    const float* W3   = (const float*)d_in[7];
    const float* b3   = (const float*)d_in[8];
    const float* W4   = (const float*)d_in[9];

    int A = in_sizes[1] / 3;
    int D = in_sizes[2] / 4;
    int F = A + 2 * D;          // 299992, divisible by 4
    int F4 = F >> 2;            // 74998 f4 per row
    int NCH = (F4 + CHUNK - 1) / CHUNK;  // 74

    float* ws = (float*)d_ws;
    float* x = ws;                              // F floats
    float* partial = ws + ((F + 3) & ~3);       // 256*NCH floats
    float* xb = partial + 256 * NCH;            // 256 floats
    float* w4term = xb + 256;                   // 256 floats

    int total = A + D;
    feat_kernel<<<(total + 255) / 256, 256, 0, stream>>>(pos, aidx, didx, x, A, D);

    dim3 g(NCH, 256);  // chunk fastest -> linear HBM sweep over W1
    w1_kernel<<<g, 256, 0, stream>>>(W1, x, partial, F4, NCH);

    l2_kernel<<<256, 256, 0, stream>>>(partial, b1, W2, b2, xb, NCH);
    l3_kernel<<<256, 256, 0, stream>>>(xb, W3, b3, W4, w4term);
    out_kernel<<<1, 256, 0, stream>>>(w4term, (float*)d_out);
}

// Round 7
// 70.314 us; speedup vs baseline: 3.1263x; 1.0284x over previous
//
#include <hip/hip_runtime.h>
#include <math.h>

#define KBT 2.494338785445972f
#define CHUNK 2048  // f4 elements of one W1 row per block (32KB)

typedef float f4 __attribute__((ext_vector_type(4)));

struct F3 { float x, y, z; };
__device__ inline F3 f3sub(F3 a, F3 b) { return {a.x - b.x, a.y - b.y, a.z - b.z}; }
__device__ inline F3 f3cross(F3 a, F3 b) {
    return {a.y * b.z - a.z * b.y, a.z * b.x - a.x * b.z, a.x * b.y - a.y * b.x};
}
__device__ inline float f3dot(F3 a, F3 b) { return a.x * b.x + a.y * b.y + a.z * b.z; }
__device__ inline F3 ldp(const float* __restrict__ p, int i) {
    return {p[3 * i], p[3 * i + 1], p[3 * i + 2]};
}
__device__ inline float dot4(f4 w, f4 v, float acc) {
    return fmaf(w.x, v.x, fmaf(w.y, v.y, fmaf(w.z, v.z, fmaf(w.w, v.w, acc))));
}

// Kernel 1: features x = [cos(angles) (A), cos(dih) (D), sin(dih) (D)]
__global__ __launch_bounds__(256) void feat_kernel(
    const float* __restrict__ pos, const int* __restrict__ aidx,
    const int* __restrict__ didx, float* __restrict__ x, int A, int D) {
    int i = blockIdx.x * blockDim.x + threadIdx.x;
    if (i < A) {
        int i0 = aidx[3 * i], i1 = aidx[3 * i + 1], i2 = aidx[3 * i + 2];
        F3 p0 = ldp(pos, i0), p1 = ldp(pos, i1), p2 = ldp(pos, i2);
        F3 v0 = f3sub(p0, p1), v1 = f3sub(p2, p1);
        float d = f3dot(v0, v1);
        F3 c = f3cross(v0, v1);
        float r = sqrtf(d * d + f3dot(c, c));   // = |v0||v1|
        x[i] = d / r;                            // cos(atan2(|c|, d))
    } else if (i < A + D) {
        int j = i - A;
        int i0 = didx[4 * j], i1 = didx[4 * j + 1], i2 = didx[4 * j + 2], i3 = didx[4 * j + 3];
        F3 p0 = ldp(pos, i0), p1 = ldp(pos, i1), p2 = ldp(pos, i2), p3 = ldp(pos, i3);
        F3 b1v = f3sub(p1, p0), b2v = f3sub(p2, p1), b3v = f3sub(p3, p2);
        F3 n1 = f3cross(b1v, b2v), n2 = f3cross(b2v, b3v);
        float xc = f3dot(n1, n2);                          // cos-like term
        float b2n = sqrtf(f3dot(b2v, b2v));
        F3 cr = f3cross(n1, n2);
        float yc = f3dot(cr, b2v) / b2n;                   // sin-like term
        float r = sqrtf(xc * xc + yc * yc);
        x[A + j] = xc / r;        // cos(dihedral)
        x[A + D + j] = yc / r;    // sin(dihedral)
    }
}

// Kernel 2: y1 partials, linear-sweep layout, 8-deep ILP.
// grid = (NCH chunks, 256 rows); blockIdx.x fastest -> consecutive block ids
// walk a contiguous sliding window of W1 (linear HBM stream).
// Each block: 32KB contiguous W1 (nt, 8 loads/thread) + 32KB L2-hot x slice.
__global__ __launch_bounds__(256) void w1_kernel(
    const float* __restrict__ W1, const float* __restrict__ x,
    float* __restrict__ partial, int F4, int NCH) {
    int c = blockIdx.x, r = blockIdx.y;
    const f4* __restrict__ row = (const f4*)W1 + (size_t)r * F4;
    const f4* __restrict__ xv = (const f4*)x;
    int base = c * CHUNK + (int)threadIdx.x;
    float a0 = 0.0f, a1 = 0.0f, a2 = 0.0f, a3 = 0.0f;
    float a4 = 0.0f, a5 = 0.0f, a6 = 0.0f, a7 = 0.0f;
    if (base + 1792 < F4) {  // full chunk fast path: 8 independent streams
        f4 w0 = __builtin_nontemporal_load(&row[base]);
        f4 w1 = __builtin_nontemporal_load(&row[base + 256]);
        f4 w2 = __builtin_nontemporal_load(&row[base + 512]);
        f4 w3 = __builtin_nontemporal_load(&row[base + 768]);
        f4 w4 = __builtin_nontemporal_load(&row[base + 1024]);
        f4 w5 = __builtin_nontemporal_load(&row[base + 1280]);
        f4 w6 = __builtin_nontemporal_load(&row[base + 1536]);
        f4 w7 = __builtin_nontemporal_load(&row[base + 1792]);
        a0 = dot4(w0, xv[base], a0);
        a1 = dot4(w1, xv[base + 256], a1);
        a2 = dot4(w2, xv[base + 512], a2);
        a3 = dot4(w3, xv[base + 768], a3);
        a4 = dot4(w4, xv[base + 1024], a4);
        a5 = dot4(w5, xv[base + 1280], a5);
        a6 = dot4(w6, xv[base + 1536], a6);
        a7 = dot4(w7, xv[base + 1792], a7);
    } else {
        #pragma unroll
        for (int u = 0; u < 8; ++u) {
            int i = base + u * 256;
            if (i < F4) a0 = dot4(__builtin_nontemporal_load(&row[i]), xv[i], a0);
        }
    }
    float acc = ((a0 + a1) + (a2 + a3)) + ((a4 + a5) + (a6 + a7));
    #pragma unroll
    for (int off = 32; off; off >>= 1) acc += __shfl_down(acc, off);
    __shared__ float lds[4];
    int wave = threadIdx.x >> 6, lane = threadIdx.x & 63;
    if (lane == 0) lds[wave] = acc;
    __syncthreads();
    if (threadIdx.x == 0) partial[r * NCH + c] = lds[0] + lds[1] + lds[2] + lds[3];
}

// Kernel 3: layer 2, one block per output row. Each block redundantly
// finishes layer 1 from L2-hot partials.
__global__ __launch_bounds__(256) void l2_kernel(
    const float* __restrict__ partial, const float* __restrict__ b1,
    const float* __restrict__ W2, const float* __restrict__ b2,
    float* __restrict__ xb, int NCH) {
    __shared__ float xa[256];
    __shared__ float lds[4];
    int t = threadIdx.x, r = blockIdx.x;
    float s = 0.0f;
    #pragma unroll 8
    for (int c = 0; c < NCH; ++c) s += partial[t * NCH + c];
    xa[t] = tanhf(s + b1[t]);
    __syncthreads();
    float v = W2[(r << 8) + t] * xa[t];
    #pragma unroll
    for (int off = 32; off; off >>= 1) v += __shfl_down(v, off);
    if ((t & 63) == 0) lds[t >> 6] = v;
    __syncthreads();
    if (t == 0) xb[r] = tanhf(lds[0] + lds[1] + lds[2] + lds[3] + b2[r]);
}

// Kernel 4: layer 3 + W4 elementwise, one block per row.
__global__ __launch_bounds__(256) void l3_kernel(
    const float* __restrict__ xb, const float* __restrict__ W3,
    const float* __restrict__ b3, const float* __restrict__ W4,
    float* __restrict__ w4term) {
    __shared__ float lds[4];
    int t = threadIdx.x, r = blockIdx.x;
    float v = W3[(r << 8) + t] * xb[t];
    #pragma unroll
    for (int off = 32; off; off >>= 1) v += __shfl_down(v, off);
    if ((t & 63) == 0) lds[t >> 6] = v;
    __syncthreads();
    if (t == 0) w4term[r] = W4[r] * tanhf(lds[0] + lds[1] + lds[2] + lds[3] + b3[r]);
}

// Kernel 5: final 256 -> scalar
__global__ __launch_bounds__(256) void out_kernel(
    const float* __restrict__ w4term, float* __restrict__ out) {
    __shared__ float lds[4];
    int t = threadIdx.x;
    float v = w4term[t];
    #pragma unroll
    for (int off = 32; off; off >>= 1) v += __shfl_down(v, off);
    if ((t & 63) == 0) lds[t >> 6] = v;
    __syncthreads();
    if (t == 0) out[0] = KBT * (lds[0] + lds[1] + lds[2] + lds[3]);
}

extern "C" void kernel_launch(void* const* d_in, const int* in_sizes, int n_in,
                              void* d_out, int out_size, void* d_ws, size_t ws_size,
                              hipStream_t stream) {
    const float* pos  = (const float*)d_in[0];
    const int*   aidx = (const int*)d_in[1];
    const int*   didx = (const int*)d_in[2];
    const float* W1   = (const float*)d_in[3];
    const float* b1   = (const float*)d_in[4];
    const float* W2   = (const float*)d_in[5];
    const float* b2   = (const float*)d_in[6];
    const float* W3   = (const float*)d_in[7];
    const float* b3   = (const float*)d_in[8];
    const float* W4   = (const float*)d_in[9];

    int A = in_sizes[1] / 3;
    int D = in_sizes[2] / 4;
    int F = A + 2 * D;          // 299992, divisible by 4
    int F4 = F >> 2;            // 74998 f4 per row
    int NCH = (F4 + CHUNK - 1) / CHUNK;  // 37

    float* ws = (float*)d_ws;
    float* x = ws;                              // F floats
    float* partial = ws + ((F + 3) & ~3);       // 256*NCH floats
    float* xb = partial + 256 * NCH;            // 256 floats
    float* w4term = xb + 256;                   // 256 floats

    int total = A + D;
    feat_kernel<<<(total + 255) / 256, 256, 0, stream>>>(pos, aidx, didx, x, A, D);

    dim3 g(NCH, 256);  // chunk fastest -> linear HBM sweep over W1
    w1_kernel<<<g, 256, 0, stream>>>(W1, x, partial, F4, NCH);

    l2_kernel<<<256, 256, 0, stream>>>(partial, b1, W2, b2, xb, NCH);
    l3_kernel<<<256, 256, 0, stream>>>(xb, W3, b3, W4, w4term);
    out_kernel<<<1, 256, 0, stream>>>(w4term, (float*)d_out);
}